// Round 12
// baseline (93.109 us; speedup 1.0000x reference)
//
#include <hip/hip_runtime.h>
#include <stdint.h>

typedef float    f32x4  __attribute__((ext_vector_type(4)));
typedef __bf16   bf16x8 __attribute__((ext_vector_type(8)));
typedef uint32_t u32x4  __attribute__((ext_vector_type(4)));
typedef unsigned short u16x4 __attribute__((ext_vector_type(4)));

#define AS1 __attribute__((address_space(1)))
#define AS3 __attribute__((address_space(3)))

__device__ __forceinline__ unsigned short f2bf_bits(float f) {
  uint32_t u = __builtin_bit_cast(uint32_t, f);
  u += 0x7fffu + ((u >> 16) & 1u);      // RNE to bf16
  return (unsigned short)(u >> 16);
}

// ---------------- kernel 0: At[col][k] (bf16) = A[k][col] ----------------
__global__ void k_transpose_cvt(const float* __restrict__ A,
                                unsigned short* __restrict__ At) {
  int n = blockIdx.x * blockDim.x + threadIdx.x;  // 65536 threads
  int o = n << 2;
  int col = o >> 8;
  int k   = o & 255;
  u16x4 v;
#pragma unroll
  for (int j = 0; j < 4; ++j) v[j] = f2bf_bits(A[(size_t)(k + j) * 1024 + col]);
  *reinterpret_cast<u16x4*>(At + o) = v;
}

// ---------------- kernel 1: barrier-free fused GEMM + fill + diag --------
// R9 structure (best measured: 77.9us), surgical changes only:
//  (1) 4 fill chunks (60..63) issued as the FIRST instructions — write
//      stream live from cycle 0, draining under the x-load latency;
//  (2) loop t=0..59 identical to R9 (uniform [8L,4S]/iter, vmcnt(40));
//      tails t=60..63 compute-only with exact vmcnt(36/24/12/0).
// 256 blocks x 256 threads; wave w owns group g=bIdx*4+w exclusively:
// 64 x-rows as 4 MFMA row-groups sharing each B-fragment (4x ds amortize),
// wave-private 4x8KB LDS buffers, depth-3 prefetch, ZERO barriers.
__launch_bounds__(256, 1)
__global__ void k_fused(const float* __restrict__ x,
                        const unsigned short* __restrict__ At,
                        float* __restrict__ out) {
  __shared__ alignas(16) char lds[4][4][8192];   // [wave][buf][8KB tile]

  const int tid  = threadIdx.x;
  const int lane = tid & 63;
  const int w    = tid >> 6;            // wave 0..3
  const int g    = blockIdx.x * 4 + w;  // this wave's group (0..1023)

  const int col = lane & 15;            // A row / B col / C col
  const int hi  = lane >> 4;            // k-subblock select

  float* og = out + (size_t)g * 65536;   // wave's exclusive 256KB group slab
  const f32x4 z4 = {0.f, 0.f, 0.f, 0.f};

  // ---- (1) fill chunks 60..63 FIRST: store stream live from cycle 0 ----
#pragma unroll
  for (int c = 60; c < 64; ++c) {
    float* zp = og + c * 1024 + lane * 4;
#pragma unroll
    for (int q = 0; q < 4; ++q)
      __builtin_nontemporal_store(z4, reinterpret_cast<f32x4*>(zp + q * 256));
  }
  __builtin_amdgcn_sched_barrier(0);

  // staging source offsets: LDS linear chunk p (16B) <- global (p ^ swz(p));
  // swz flips bits 4..6 keyed by bits 9..11 -> conflict-free b128 reads
  uint32_t soff[8];
#pragma unroll
  for (int i = 0; i < 8; ++i) {
    uint32_t p = (uint32_t)(i * 1024 + lane * 16);
    soff[i] = p ^ (((p >> 9) & 7u) << 4);
  }

  // prefetch tiles 0..2 into this wave's buffers 0..2
#pragma unroll
  for (int t = 0; t < 3; ++t) {
    const char* src = (const char*)At + (size_t)t * 8192;
    char* dst = lds[w][t];
#pragma unroll
    for (int i = 0; i < 8; ++i)
      __builtin_amdgcn_global_load_lds((const AS1 uint32_t*)(src + soff[i]),
                                       (AS3 uint32_t*)(dst + i * 1024), 16, 0, 0);
  }
  __builtin_amdgcn_sched_barrier(0);   // keep x loads below the prefetches

  // x fragments: rg r -> x-row g*64 + r*16 + col, k = s*32 + hi*8
  bf16x8 xf[4][8];
#pragma unroll
  for (int r = 0; r < 4; ++r) {
    const float* xr = x + (size_t)(g * 64 + r * 16 + col) * 256;
#pragma unroll
    for (int s = 0; s < 8; ++s) {
      f32x4 a = __builtin_nontemporal_load(
          reinterpret_cast<const f32x4*>(xr + s * 32 + hi * 8));
      f32x4 bq = __builtin_nontemporal_load(
          reinterpret_cast<const f32x4*>(xr + s * 32 + hi * 8 + 4));
      bf16x8 f;
      f[0] = (__bf16)a[0];  f[1] = (__bf16)a[1];
      f[2] = (__bf16)a[2];  f[3] = (__bf16)a[3];
      f[4] = (__bf16)bq[0]; f[5] = (__bf16)bq[1];
      f[6] = (__bf16)bq[2]; f[7] = (__bf16)bq[3];
      xf[r][s] = f;
    }
  }
  // drain prologue (x consumption already waited on everything older,
  // including the 16 prologue stores) -> loop counts see only loop ops
  asm volatile("s_waitcnt vmcnt(0)" ::: "memory");

  // B-frag read: byte col*512 + s*64 + hi*16, XOR (col&7)<<4; disjoint bit
  // fields -> addr(s) = rbase ^ (s<<6)
  uint32_t rbase = ((uint32_t)(col * 512 + hi * 16)) ^ ((uint32_t)(col & 7) << 4);

  float sums[4][4] = {{0.f,0.f,0.f,0.f},{0.f,0.f,0.f,0.f},
                      {0.f,0.f,0.f,0.f},{0.f,0.f,0.f,0.f}};

  auto stage = [&](int t) {   // stage tile t into this wave's buf t&3
    const char* src = (const char*)At + (size_t)t * 8192;
    char* dst = lds[w][t & 3];
#pragma unroll
    for (int i = 0; i < 8; ++i)
      __builtin_amdgcn_global_load_lds((const AS1 uint32_t*)(src + soff[i]),
                                       (AS3 uint32_t*)(dst + i * 1024), 16, 0, 0);
  };
  auto do_tile = [&](const char* buf) {
    bf16x8 bfr[8];
#pragma unroll
    for (int s = 0; s < 8; ++s) {
      uint32_t addr = rbase ^ ((uint32_t)s << 6);
      bfr[s] = __builtin_bit_cast(
          bf16x8, *reinterpret_cast<const u32x4*>(buf + addr));
    }
    f32x4 acc[4] = {{0.f,0.f,0.f,0.f},{0.f,0.f,0.f,0.f},
                    {0.f,0.f,0.f,0.f},{0.f,0.f,0.f,0.f}};
#pragma unroll
    for (int s = 0; s < 8; ++s) {
#pragma unroll
      for (int r = 0; r < 4; ++r)
        acc[r] = __builtin_amdgcn_mfma_f32_16x16x32_bf16(xf[r][s], bfr[s],
                                                         acc[r], 0, 0, 0);
    }
#pragma unroll
    for (int r = 0; r < 4; ++r)
#pragma unroll
      for (int j = 0; j < 4; ++j) {
        float z = acc[r][j];
        float sig = __builtin_amdgcn_rcpf(1.0f + __expf(-z));
        sums[r][j] += z * sig;
      }
  };

  // ---- main loop t=0..59: uniform [8L(t+3), 4S(t)] per iter (R9) ----
  for (int t = 0; t < 60; ++t) {
    asm volatile("s_waitcnt lgkmcnt(0)" ::: "memory");  // buf reads done
    stage(t + 3);
    __builtin_amdgcn_sched_barrier(0);   // pin [8L] before the stores
    {
      float* zp = og + t * 1024 + lane * 4;
#pragma unroll
      for (int q = 0; q < 4; ++q)
        __builtin_nontemporal_store(z4, reinterpret_cast<f32x4*>(zp + q * 256));
    }
    // younger than L(t) (issued iter t-3): 4S(t-3)+12(t-2)+12(t-1)+12(t)=40
    asm volatile("s_waitcnt vmcnt(40)" ::: "memory");
    do_tile(lds[w][t & 3]);
  }
  // ---- tails t=60..63 (fills done in prologue; exact counts) ----
  asm volatile("s_waitcnt lgkmcnt(0)" ::: "memory");
  stage(63);                                           // 8L
  asm volatile("s_waitcnt vmcnt(36)" ::: "memory");    // 4S(57)+12+12+8
  do_tile(lds[w][0]);                                  // t=60
  asm volatile("s_waitcnt vmcnt(24)" ::: "memory");    // 4S(58)+12(59)+8
  do_tile(lds[w][1]);                                  // t=61
  asm volatile("s_waitcnt vmcnt(12)" ::: "memory");    // 4S(59)+8
  do_tile(lds[w][2]);                                  // t=62
  asm volatile("s_waitcnt vmcnt(0)" ::: "memory");     // all loads+stores done
  do_tile(lds[w][3]);                                  // t=63

  // reduce over the 16 column-lanes (C layout: col = lane&15)
#pragma unroll
  for (int r = 0; r < 4; ++r)
#pragma unroll
    for (int j = 0; j < 4; ++j) {
      float v = sums[r][j];
      v += __shfl_xor(v, 1, 64);
      v += __shfl_xor(v, 2, 64);
      v += __shfl_xor(v, 4, 64);
      v += __shfl_xor(v, 8, 64);
      sums[r][j] = v;
    }

  // diag entries (zero-stores drained above; same-wave ordering; wave owns
  // the whole group slab -> race-free)
  if (col == 0) {
#pragma unroll
    for (int r = 0; r < 4; ++r)
#pragma unroll
      for (int j = 0; j < 4; ++j) {
        int c = r * 16 + hi * 4 + j;     // x-row within group, 0..63
        float s = sums[r][j];
        og[(2 * c) * 256 + 128 + 2 * c]     =  s;   // out[g, i, 128+i], i=2c
        og[(2 * c + 1) * 256 + 129 + 2 * c] =  s;   // i=2c+1
        og[(128 + 2 * c) * 256 + 2 * c]     = -s;   // out[g, 128+i, i]
        og[(129 + 2 * c) * 256 + 2 * c + 1] = -s;
      }
  }
}

extern "C" void kernel_launch(void* const* d_in, const int* in_sizes, int n_in,
                              void* d_out, int out_size, void* d_ws, size_t ws_size,
                              hipStream_t stream) {
  const float* x = (const float*)d_in[0];   // [65536, 256]
  const float* A = (const float*)d_in[1];   // [256, 1024]
  float* out = (float*)d_out;               // [1024, 256, 256]
  unsigned short* At = (unsigned short*)d_ws;  // 512 KB bf16 transposed weights

  k_transpose_cvt<<<256, 256, 0, stream>>>(A, At);
  k_fused<<<256, 256, 0, stream>>>(x, At, out);
}

// Round 13
// 78.520 us; speedup vs baseline: 1.1858x; 1.1858x over previous
//
#include <hip/hip_runtime.h>
#include <stdint.h>

typedef float    f32x4  __attribute__((ext_vector_type(4)));
typedef __bf16   bf16x8 __attribute__((ext_vector_type(8)));
typedef uint32_t u32x4  __attribute__((ext_vector_type(4)));
typedef unsigned short u16x4 __attribute__((ext_vector_type(4)));

#define AS1 __attribute__((address_space(1)))
#define AS3 __attribute__((address_space(3)))

__device__ __forceinline__ unsigned short f2bf_bits(float f) {
  uint32_t u = __builtin_bit_cast(uint32_t, f);
  u += 0x7fffu + ((u >> 16) & 1u);      // RNE to bf16
  return (unsigned short)(u >> 16);
}

// ---------------- kernel 0: At[col][k] (bf16) = A[k][col] ----------------
// A: [256][1024] f32  ->  At: [1024][256] bf16 (in d_ws)
__global__ void k_transpose_cvt(const float* __restrict__ A,
                                unsigned short* __restrict__ At) {
  int n = blockIdx.x * blockDim.x + threadIdx.x;  // 65536 threads
  int o = n << 2;                                 // 4 elements per thread
  int col = o >> 8;
  int k   = o & 255;
  u16x4 v;
#pragma unroll
  for (int j = 0; j < 4; ++j) v[j] = f2bf_bits(A[(size_t)(k + j) * 1024 + col]);
  *reinterpret_cast<u16x4*>(At + o) = v;          // coalesced write
}

// ---------------- kernel 1: barrier-free fused GEMM + fill + diag --------
// (R9 verbatim — best measured: 77.9us.)
// 256 blocks x 256 threads. Wave w exclusively owns group g = bIdx*4+w:
//  - GEMM: 64 x-rows as 4 MFMA row-groups sharing each B-fragment read
//    (4x LDS-read amortization)
//  - B-tiles staged into WAVE-PRIVATE LDS buffers (4 x 8KB per wave),
//    3-deep prefetch, synced only by this wave's counted vmcnt — NO barriers
//  - fused zero-fill: 4KB contiguous (4 full out-rows) per tile
//  - epilogue: own vmcnt(0), shfl-reduce, write 256 diag entries (same-wave
//    ordering after drain -> race-free)
__launch_bounds__(256, 1)
__global__ void k_fused(const float* __restrict__ x,
                        const unsigned short* __restrict__ At,
                        float* __restrict__ out) {
  __shared__ alignas(16) char lds[4][4][8192];   // [wave][buf][8KB tile]

  const int tid  = threadIdx.x;
  const int lane = tid & 63;
  const int w    = tid >> 6;            // wave 0..3
  const int g    = blockIdx.x * 4 + w;  // this wave's group (0..1023)

  const int col = lane & 15;            // A row / B col / C col
  const int hi  = lane >> 4;            // k-subblock select

  // staging source offsets: LDS linear chunk p (16B) <- global (p ^ swz(p));
  // swz flips bits 4..6 keyed by bits 9..11 (col) -> conflict-free b128 reads
  uint32_t soff[8];
#pragma unroll
  for (int i = 0; i < 8; ++i) {
    uint32_t p = (uint32_t)(i * 1024 + lane * 16);
    soff[i] = p ^ (((p >> 9) & 7u) << 4);
  }

  // ---- prologue: prefetch tiles 0..2 into this wave's buffers 0..2 ------
#pragma unroll
  for (int t = 0; t < 3; ++t) {
    const char* src = (const char*)At + (size_t)t * 8192;
    char* dst = lds[w][t];
#pragma unroll
    for (int i = 0; i < 8; ++i)
      __builtin_amdgcn_global_load_lds((const AS1 uint32_t*)(src + soff[i]),
                                       (AS3 uint32_t*)(dst + i * 1024), 16, 0, 0);
  }
  __builtin_amdgcn_sched_barrier(0);   // keep x loads below the prefetches

  // ---- x fragments: rg r -> x-row g*64 + r*16 + col, k = s*32 + hi*8 ----
  bf16x8 xf[4][8];
#pragma unroll
  for (int r = 0; r < 4; ++r) {
    const float* xr = x + (size_t)(g * 64 + r * 16 + col) * 256;
#pragma unroll
    for (int s = 0; s < 8; ++s) {
      f32x4 a = __builtin_nontemporal_load(
          reinterpret_cast<const f32x4*>(xr + s * 32 + hi * 8));
      f32x4 bq = __builtin_nontemporal_load(
          reinterpret_cast<const f32x4*>(xr + s * 32 + hi * 8 + 4));
      bf16x8 f;
      f[0] = (__bf16)a[0];  f[1] = (__bf16)a[1];
      f[2] = (__bf16)a[2];  f[3] = (__bf16)a[3];
      f[4] = (__bf16)bq[0]; f[5] = (__bf16)bq[1];
      f[6] = (__bf16)bq[2]; f[7] = (__bf16)bq[3];
      xf[r][s] = f;
    }
  }
  // drain prologue -> loop's counted vmcnt sees only loop ops
  asm volatile("s_waitcnt vmcnt(0)" ::: "memory");

  // B-frag read: byte col*512 + s*64 + hi*16, XOR (col&7)<<4; disjoint bit
  // fields -> addr(s) = rbase ^ (s<<6)
  uint32_t rbase = ((uint32_t)(col * 512 + hi * 16)) ^ ((uint32_t)(col & 7) << 4);

  float sums[4][4] = {{0.f,0.f,0.f,0.f},{0.f,0.f,0.f,0.f},
                      {0.f,0.f,0.f,0.f},{0.f,0.f,0.f,0.f}};
  float* og = out + (size_t)g * 65536;   // wave's exclusive 256KB group slab
  const f32x4 z4 = {0.f, 0.f, 0.f, 0.f};

  for (int t = 0; t < 64; ++t) {
    // buf (t+3)&3's previous ds_reads (iter t-1) are consumed; make it explicit
    asm volatile("s_waitcnt lgkmcnt(0)" ::: "memory");
    // prefetch tile t+3 into this wave's buf (t+3)&3 (wrapped: uniform 12-op
    // per-iter vmem pattern keeps the vmcnt count exact every iteration)
    {
      int pt = (t + 3) & 63;
      const char* src = (const char*)At + (size_t)pt * 8192;
      char* dst = lds[w][(t + 3) & 3];
#pragma unroll
      for (int i = 0; i < 8; ++i)
        __builtin_amdgcn_global_load_lds((const AS1 uint32_t*)(src + soff[i]),
                                         (AS3 uint32_t*)(dst + i * 1024), 16, 0, 0);
    }
    __builtin_amdgcn_sched_barrier(0);   // pin [8L] before the stores
    // fused zero-fill: 4 contiguous out-rows (4KB) of own slab, no holes
    {
      float* zp = og + t * 1024 + lane * 4;
#pragma unroll
      for (int q = 0; q < 4; ++q)
        __builtin_nontemporal_store(z4, reinterpret_cast<f32x4*>(zp + q * 256));
    }
    // wait for THIS tile's 8 loads (issued 3 iters ago). Ops younger than the
    // last L(t): 4S(t-3) + 12(t-2) + 12(t-1) + 12(t) = 40 -> vmcnt(40).
    // ~40 outstanding vmem ops keep the write stream continuously fed.
    asm volatile("s_waitcnt vmcnt(40)" ::: "memory");

    const char* buf = lds[w][t & 3];
    bf16x8 bfr[8];
#pragma unroll
    for (int s = 0; s < 8; ++s) {
      uint32_t addr = rbase ^ ((uint32_t)s << 6);
      bfr[s] = __builtin_bit_cast(
          bf16x8, *reinterpret_cast<const u32x4*>(buf + addr));
    }
    // 4 independent MFMA chains (one per row-group) share each bfr[s]
    f32x4 acc[4] = {{0.f,0.f,0.f,0.f},{0.f,0.f,0.f,0.f},
                    {0.f,0.f,0.f,0.f},{0.f,0.f,0.f,0.f}};
#pragma unroll
    for (int s = 0; s < 8; ++s) {
#pragma unroll
      for (int r = 0; r < 4; ++r)
        acc[r] = __builtin_amdgcn_mfma_f32_16x16x32_bf16(xf[r][s], bfr[s],
                                                         acc[r], 0, 0, 0);
    }
#pragma unroll
    for (int r = 0; r < 4; ++r)
#pragma unroll
      for (int j = 0; j < 4; ++j) {
        float z = acc[r][j];
        float sig = __builtin_amdgcn_rcpf(1.0f + __expf(-z));
        sums[r][j] += z * sig;
      }
  }

  // drain own zero-stores; subsequent diag writes to the same lines are
  // same-wave ordered. No cross-wave/cross-block hazard (exclusive slab).
  asm volatile("s_waitcnt vmcnt(0)" ::: "memory");

  // reduce over the 16 column-lanes (C layout: col = lane&15)
#pragma unroll
  for (int r = 0; r < 4; ++r)
#pragma unroll
    for (int j = 0; j < 4; ++j) {
      float v = sums[r][j];
      v += __shfl_xor(v, 1, 64);
      v += __shfl_xor(v, 2, 64);
      v += __shfl_xor(v, 4, 64);
      v += __shfl_xor(v, 8, 64);
      sums[r][j] = v;
    }

  if (col == 0) {
#pragma unroll
    for (int r = 0; r < 4; ++r)
#pragma unroll
      for (int j = 0; j < 4; ++j) {
        int c = r * 16 + hi * 4 + j;     // x-row within group, 0..63
        float s = sums[r][j];
        og[(2 * c) * 256 + 128 + 2 * c]     =  s;   // out[g, i, 128+i], i=2c
        og[(2 * c + 1) * 256 + 129 + 2 * c] =  s;   // i=2c+1
        og[(128 + 2 * c) * 256 + 2 * c]     = -s;   // out[g, 128+i, i]
        og[(129 + 2 * c) * 256 + 2 * c + 1] = -s;
      }
  }
}

extern "C" void kernel_launch(void* const* d_in, const int* in_sizes, int n_in,
                              void* d_out, int out_size, void* d_ws, size_t ws_size,
                              hipStream_t stream) {
  const float* x = (const float*)d_in[0];   // [65536, 256]
  const float* A = (const float*)d_in[1];   // [256, 1024]
  float* out = (float*)d_out;               // [1024, 256, 256]
  unsigned short* At = (unsigned short*)d_ws;  // 512 KB bf16 transposed weights

  k_transpose_cvt<<<256, 256, 0, stream>>>(A, At);
  k_fused<<<256, 256, 0, stream>>>(x, At, out);
}

// Round 14
// 78.465 us; speedup vs baseline: 1.1866x; 1.0007x over previous
//
#include <hip/hip_runtime.h>
#include <stdint.h>

typedef float    f32x4  __attribute__((ext_vector_type(4)));
typedef __bf16   bf16x8 __attribute__((ext_vector_type(8)));
typedef uint32_t u32x4  __attribute__((ext_vector_type(4)));
typedef unsigned short u16x4 __attribute__((ext_vector_type(4)));

#define AS1 __attribute__((address_space(1)))
#define AS3 __attribute__((address_space(3)))

__device__ __forceinline__ unsigned short f2bf_bits(float f) {
  uint32_t u = __builtin_bit_cast(uint32_t, f);
  u += 0x7fffu + ((u >> 16) & 1u);      // RNE to bf16
  return (unsigned short)(u >> 16);
}

// ---------------- kernel 0: At[col][k] (bf16) = A[k][col] ----------------
__global__ void k_transpose_cvt(const float* __restrict__ A,
                                unsigned short* __restrict__ At) {
  int n = blockIdx.x * blockDim.x + threadIdx.x;  // 65536 threads
  int o = n << 2;
  int col = o >> 8;
  int k   = o & 255;
  u16x4 v;
#pragma unroll
  for (int j = 0; j < 4; ++j) v[j] = f2bf_bits(A[(size_t)(k + j) * 1024 + col]);
  *reinterpret_cast<u16x4*>(At + o) = v;
}

// ---------------- kernel 1: N-split fused GEMM + fill + diag -------------
// 512 blocks x 256 threads, 2 blocks/CU (8 waves/CU = 2 waves/SIMD).
// Block = 2 groups; the pair of waves (w, w^1) shares group g = bIdx*2+(w>>1)
// and splits its 64 N-tiles: th=w&1 -> tiles th*32..th*32+31.  Each wave
// keeps ALL 4 row-groups (R9's 4x ds amortization).  Wave-private 2x8KB LDS
// staging, depth-1 prefetch, counted vmcnt, NO in-loop barriers.  Each wave
// zero-fills rows th*128..th*128+127 (contiguous 128KB half-slab).
// Epilogue: own vmcnt(0); partial row-sums exchanged via 1KB LDS + one
// __syncthreads; wave th writes the diag entries in ITS half (top/bottom).
__launch_bounds__(256, 2)
__global__ void k_fused(const float* __restrict__ x,
                        const unsigned short* __restrict__ At,
                        float* __restrict__ out) {
  __shared__ alignas(16) char lds[4][2][8192];   // [wave][buf][8KB tile]
  __shared__ float sarr[4][64];                  // per-wave partial row-sums

  const int tid  = threadIdx.x;
  const int lane = tid & 63;
  const int w    = tid >> 6;              // wave 0..3
  const int th   = w & 1;                 // tile-half / fill-half
  const int g    = blockIdx.x * 2 + (w >> 1);   // group 0..1023

  const int col = lane & 15;              // A row / B col / C col
  const int hi  = lane >> 4;              // k-subblock select

  // staging source offsets: LDS linear chunk p (16B) <- global (p ^ swz(p));
  // swz flips bits 4..6 keyed by bits 9..11 -> conflict-free b128 reads
  uint32_t soff[8];
#pragma unroll
  for (int i = 0; i < 8; ++i) {
    uint32_t p = (uint32_t)(i * 1024 + lane * 16);
    soff[i] = p ^ (((p >> 9) & 7u) << 4);
  }

  auto stage = [&](int T) {   // stage global tile T into wave buf T&1
    const char* src = (const char*)At + (size_t)T * 8192;
    char* dst = lds[w][T & 1];
#pragma unroll
    for (int i = 0; i < 8; ++i)
      __builtin_amdgcn_global_load_lds((const AS1 uint32_t*)(src + soff[i]),
                                       (AS3 uint32_t*)(dst + i * 1024), 16, 0, 0);
  };

  // ---- prologue: stage first tile of this wave's range ----
  stage(th * 32);
  __builtin_amdgcn_sched_barrier(0);   // keep x loads below the prefetch

  // ---- x fragments (PLAIN loads: sibling wave re-reads -> L2 hit) ----
  bf16x8 xf[4][8];
#pragma unroll
  for (int r = 0; r < 4; ++r) {
    const float* xr = x + (size_t)(g * 64 + r * 16 + col) * 256;
#pragma unroll
    for (int s = 0; s < 8; ++s) {
      f32x4 a  = *reinterpret_cast<const f32x4*>(xr + s * 32 + hi * 8);
      f32x4 bq = *reinterpret_cast<const f32x4*>(xr + s * 32 + hi * 8 + 4);
      bf16x8 f;
      f[0] = (__bf16)a[0];  f[1] = (__bf16)a[1];
      f[2] = (__bf16)a[2];  f[3] = (__bf16)a[3];
      f[4] = (__bf16)bq[0]; f[5] = (__bf16)bq[1];
      f[6] = (__bf16)bq[2]; f[7] = (__bf16)bq[3];
      xf[r][s] = f;
    }
  }
  // drain prologue -> loop's counted vmcnt sees only loop ops
  asm volatile("s_waitcnt vmcnt(0)" ::: "memory");

  // B-frag read: byte col*512 + s*64 + hi*16, XOR (col&7)<<4
  uint32_t rbase = ((uint32_t)(col * 512 + hi * 16)) ^ ((uint32_t)(col & 7) << 4);

  float sums[4][4] = {{0.f,0.f,0.f,0.f},{0.f,0.f,0.f,0.f},
                      {0.f,0.f,0.f,0.f},{0.f,0.f,0.f,0.f}};
  float* og = out + (size_t)g * 65536;          // group slab
  float* fillbase = og + (size_t)th * 32768 + lane * 4;  // wave's half
  const f32x4 z4 = {0.f, 0.f, 0.f, 0.f};

  auto do_tile = [&](const char* buf) {
    bf16x8 bfr[8];
#pragma unroll
    for (int s = 0; s < 8; ++s) {
      uint32_t addr = rbase ^ ((uint32_t)s << 6);
      bfr[s] = __builtin_bit_cast(
          bf16x8, *reinterpret_cast<const u32x4*>(buf + addr));
    }
    f32x4 acc[4] = {{0.f,0.f,0.f,0.f},{0.f,0.f,0.f,0.f},
                    {0.f,0.f,0.f,0.f},{0.f,0.f,0.f,0.f}};
#pragma unroll
    for (int s = 0; s < 8; ++s) {
#pragma unroll
      for (int r = 0; r < 4; ++r)
        acc[r] = __builtin_amdgcn_mfma_f32_16x16x32_bf16(xf[r][s], bfr[s],
                                                         acc[r], 0, 0, 0);
    }
#pragma unroll
    for (int r = 0; r < 4; ++r)
#pragma unroll
      for (int j = 0; j < 4; ++j) {
        float z = acc[r][j];
        float sig = __builtin_amdgcn_rcpf(1.0f + __expf(-z));
        sums[r][j] += z * sig;
      }
  };

  // ---- main loop t=0..30: per iter [8L(T+1), 4S(t)], wait vmcnt(16) ----
  // Younger than L(t) (issued prev iter): 4S(t-1) + 8L(t+1) + 4S(t) = 16.
  // t=0: only 12 outstanding -> trivially satisfied (prologue drained).
  for (int t = 0; t < 31; ++t) {
    asm volatile("s_waitcnt lgkmcnt(0)" ::: "memory");  // buf reads done
    stage(th * 32 + t + 1);
    __builtin_amdgcn_sched_barrier(0);   // pin [8L] before the stores
    {
      float* zp = fillbase + t * 1024;   // 4 contiguous out-rows (4KB)
#pragma unroll
      for (int q = 0; q < 4; ++q)
        __builtin_nontemporal_store(z4, reinterpret_cast<f32x4*>(zp + q * 256));
    }
    asm volatile("s_waitcnt vmcnt(16)" ::: "memory");
    do_tile(lds[w][t & 1]);
  }
  // ---- tail t=31: fill, wait 4S(30)+4S(31)=8, compute ----
  {
    float* zp = fillbase + 31 * 1024;
#pragma unroll
    for (int q = 0; q < 4; ++q)
      __builtin_nontemporal_store(z4, reinterpret_cast<f32x4*>(zp + q * 256));
  }
  asm volatile("s_waitcnt vmcnt(8)" ::: "memory");
  do_tile(lds[w][31 & 1]);

  // drain own fills (required before diag into own half after barrier)
  asm volatile("s_waitcnt vmcnt(0)" ::: "memory");

  // ---- reduce over the 16 column-lanes; stash partials in LDS ----
#pragma unroll
  for (int r = 0; r < 4; ++r)
#pragma unroll
    for (int j = 0; j < 4; ++j) {
      float v = sums[r][j];
      v += __shfl_xor(v, 1, 64);
      v += __shfl_xor(v, 2, 64);
      v += __shfl_xor(v, 4, 64);
      v += __shfl_xor(v, 8, 64);
      sums[r][j] = v;
    }
  if (col == 0) {            // lanes 0,16,32,48 (hi = 0..3)
#pragma unroll
    for (int r = 0; r < 4; ++r)
#pragma unroll
      for (int j = 0; j < 4; ++j)
        sarr[w][r * 16 + hi * 4 + j] = sums[r][j];
  }
  __syncthreads();           // partials visible; all waves' fills drained

  // ---- diag: wave th writes the entries lying in its own fill half ----
  {
    int c = lane;                          // x-row within group, 0..63
    float s = sarr[w][c] + sarr[w ^ 1][c]; // full row-sum over 1024 cols
    if (th == 0) {
      // top-right block diag: rows 2c,2c+1 (half 0), cols 128+2c,129+2c
      og[(2 * c) * 256 + 128 + 2 * c]     =  s;
      og[(2 * c + 1) * 256 + 129 + 2 * c] =  s;
    } else {
      // bottom-left block diag: rows 128+2c,129+2c (half 1), cols 2c,2c+1
      og[(128 + 2 * c) * 256 + 2 * c]     = -s;
      og[(129 + 2 * c) * 256 + 2 * c + 1] = -s;
    }
  }
}

extern "C" void kernel_launch(void* const* d_in, const int* in_sizes, int n_in,
                              void* d_out, int out_size, void* d_ws, size_t ws_size,
                              hipStream_t stream) {
  const float* x = (const float*)d_in[0];   // [65536, 256]
  const float* A = (const float*)d_in[1];   // [256, 1024]
  float* out = (float*)d_out;               // [1024, 256, 256]
  unsigned short* At = (unsigned short*)d_ws;  // 512 KB bf16 transposed weights

  k_transpose_cvt<<<256, 256, 0, stream>>>(A, At);
  k_fused<<<512, 256, 0, stream>>>(x, At, out);
}